// Round 9
// baseline (859.768 us; speedup 1.0000x reference)
//
#include <hip/hip_runtime.h>

#define N_PTS 131072
#define KC    512
#define DIM   64
#define MAXIT 5
#define NCHUNK 64
#define CHUNK_PTS (N_PTS / NCHUNK)    // 2048
#define FIXSCALE 1099511627776.0      // 2^40
#define XSTR 68                       // LDS row stride (64+4)

// ---------------------------------------------------------------------------
// c2 kernel (iter 0 only): c2[k] = sum_d C[k][d]^2, squares rounded then
// pairwise tree — identical value tree to round 2 (which passed).
// ---------------------------------------------------------------------------
__global__ __launch_bounds__(256) void c2_kernel(const float* __restrict__ C,
                                                 float* __restrict__ c2out) {
    int k = blockIdx.x * 256 + threadIdx.x;
    if (k < KC) {
        float sq[DIM];
        #pragma unroll
        for (int j = 0; j < DIM; ++j) {
            float c = C[k * DIM + j];
            sq[j] = c * c;
        }
        #pragma unroll
        for (int st = 1; st < DIM; st <<= 1)
            #pragma unroll
            for (int j = 0; j < DIM; j += 2 * st)
                sq[j] = sq[j] + sq[j + st];
        c2out[k] = sq[0];
    }
}

// ---------------------------------------------------------------------------
// assign kernel, ROUND 9: round-8 register-blocked LDS GEMM (d2 chain
// bit-identical) + register-prefetch double-buffer of the C tile + VALU diet.
//  - C tile kt+1 (4 float4/thread) + c2 (4/lane) prefetched into registers
//    before the GEMM on tile kt: the ~2k-cycle GEMM hides global latency;
//    vmcnt wait lands at next tile's ds_write (data long arrived). Barriers
//    unchanged (2/tile), no extra LDS.
//  - x2 partials combined via in-wave __shfl (staging lane 4m+q is in the
//    consumer's wave): x2p/x2f LDS arrays + t<64 divergent block removed.
//  - within-lane argmin: float '<' + index (ascending-k scan + strict '<'
//    = same first-index tie semantics); u64 monotone key built once per
//    lane for the cross-lane butterfly (unchanged from round 8).
// ---------------------------------------------------------------------------
__global__ __launch_bounds__(256) void assign_kernel(
        const float* __restrict__ X, const float* __restrict__ C,
        const float* __restrict__ c2v,
        int* __restrict__ asn, float* __restrict__ out_f) {
    __shared__ float Xt[64 * XSTR];
    __shared__ float Ct[64 * XSTR];

    const int t  = threadIdx.x;
    const int pt = t >> 2;        // 0..63: row this thread stages
    const int q  = t & 3;         // quarter (16 floats) within the row

    // ---- stage X tile + per-quarter x2 subtree (tree level 4, exact order)
    float x2part;
    {
        const float* xg = X + ((size_t)blockIdx.x * 64 + pt) * DIM + q * 16;
        float4 v0 = *(const float4*)(xg + 0);
        float4 v1 = *(const float4*)(xg + 4);
        float4 v2 = *(const float4*)(xg + 8);
        float4 v3 = *(const float4*)(xg + 12);
        float* xw = &Xt[pt * XSTR + q * 16];
        *(float4*)(xw + 0)  = v0;
        *(float4*)(xw + 4)  = v1;
        *(float4*)(xw + 8)  = v2;
        *(float4*)(xw + 12) = v3;
        float s[16] = { v0.x*v0.x, v0.y*v0.y, v0.z*v0.z, v0.w*v0.w,
                        v1.x*v1.x, v1.y*v1.y, v1.z*v1.z, v1.w*v1.w,
                        v2.x*v2.x, v2.y*v2.y, v2.z*v2.z, v2.w*v2.w,
                        v3.x*v3.x, v3.y*v3.y, v3.z*v3.z, v3.w*v3.w };
        #pragma unroll
        for (int st = 1; st < 16; st <<= 1)
            #pragma unroll
            for (int j2 = 0; j2 < 16; j2 += 2 * st)
                s[j2] = s[j2] + s[j2 + st];
        x2part = s[0];
    }

    const int w  = t >> 6;        // wave: handles points w*16 .. w*16+15
    const int l  = t & 63;
    const int cg = l >> 2;        // 0..15 center-group
    const int pg = l & 3;         // 0..3 point-group
    const float* xb = &Xt[(w * 16 + pg * 4) * XSTR];
    const float* cb = &Ct[cg * XSTR];

    // x2 for my 4 points: partials for point m=pg*4+i live at in-wave lanes
    // 4m+q (staging thread 64w+4m+q is in wave w). Tree: (P0+P1)+(P2+P3)
    // = identical summation order to rounds 2-8.
    float xx[4];
    #pragma unroll
    for (int i = 0; i < 4; ++i) {
        int m = pg * 4 + i;
        float P0 = __shfl(x2part, 4 * m + 0, 64);
        float P1 = __shfl(x2part, 4 * m + 1, 64);
        float P2 = __shfl(x2part, 4 * m + 2, 64);
        float P3 = __shfl(x2part, 4 * m + 3, 64);
        xx[i] = (P0 + P1) + (P2 + P3);
    }

    // ---- prefetch tile 0 (C rows + c2) into registers
    float4 u0, u1, u2, u3;
    float c2r0, c2r1, c2r2, c2r3;
    {
        const float* cgp = C + (size_t)pt * DIM + q * 16;
        u0 = *(const float4*)(cgp + 0);
        u1 = *(const float4*)(cgp + 4);
        u2 = *(const float4*)(cgp + 8);
        u3 = *(const float4*)(cgp + 12);
        c2r0 = c2v[cg +  0];
        c2r1 = c2v[cg + 16];
        c2r2 = c2v[cg + 32];
        c2r3 = c2v[cg + 48];
    }

    float bd[4]  = { 3.4e38f, 3.4e38f, 3.4e38f, 3.4e38f };
    int   bki[4] = { 0, 0, 0, 0 };

    for (int kt = 0; kt < 8; ++kt) {
        __syncthreads();   // kt=0: Xt ready; kt>0: prev GEMM done with Ct
        // write the prefetched tile (vmcnt wait here — data arrived during
        // the previous tile's GEMM)
        float* cw = &Ct[pt * XSTR + q * 16];
        *(float4*)(cw + 0)  = u0;
        *(float4*)(cw + 4)  = u1;
        *(float4*)(cw + 8)  = u2;
        *(float4*)(cw + 12) = u3;
        float c2c0 = c2r0, c2c1 = c2r1, c2c2 = c2r2, c2c3 = c2r3;
        // prefetch tile kt+1 (kt=7 wraps to 0: in-bounds, unused)
        {
            int ktn = (kt + 1) & 7;
            const float* cgp = C + ((size_t)(ktn * 64 + pt)) * DIM + q * 16;
            u0 = *(const float4*)(cgp + 0);
            u1 = *(const float4*)(cgp + 4);
            u2 = *(const float4*)(cgp + 8);
            u3 = *(const float4*)(cgp + 12);
            c2r0 = c2v[ktn * 64 + cg +  0];
            c2r1 = c2v[ktn * 64 + cg + 16];
            c2r2 = c2v[ktn * 64 + cg + 32];
            c2r3 = c2v[ktn * 64 + cg + 48];
        }
        __syncthreads();

        float4 a[4][4];
        #pragma unroll
        for (int i = 0; i < 4; ++i)
            #pragma unroll
            for (int j = 0; j < 4; ++j)
                a[i][j] = make_float4(0.f, 0.f, 0.f, 0.f);

        #pragma unroll 4
        for (int c = 0; c < 16; ++c) {
            float4 xf[4], cf[4];
            #pragma unroll
            for (int i = 0; i < 4; ++i)
                xf[i] = *(const float4*)&xb[i * XSTR + c * 4];
            #pragma unroll
            for (int j = 0; j < 4; ++j)
                cf[j] = *(const float4*)&cb[j * (16 * XSTR) + c * 4];
            #pragma unroll
            for (int i = 0; i < 4; ++i)
                #pragma unroll
                for (int j = 0; j < 4; ++j) {
                    a[i][j].x = fmaf(xf[i].x, cf[j].x, a[i][j].x);
                    a[i][j].y = fmaf(xf[i].y, cf[j].y, a[i][j].y);
                    a[i][j].z = fmaf(xf[i].z, cf[j].z, a[i][j].z);
                    a[i][j].w = fmaf(xf[i].w, cf[j].w, a[i][j].w);
                }
        }

        const float c2c[4] = { c2c0, c2c1, c2c2, c2c3 };
        #pragma unroll
        for (int j = 0; j < 4; ++j) {
            float cc = c2c[j];
            int kk = kt * 64 + cg + 16 * j;
            #pragma unroll
            for (int i = 0; i < 4; ++i) {
                float dot = (a[i][j].x + a[i][j].y) + (a[i][j].z + a[i][j].w);
                float tt  = xx[i] + cc;          // rounded at d2 scale, matches np
                float d2  = tt - 2.0f * dot;     // 2*dot exact
                if (d2 < bd[i]) { bd[i] = d2; bki[i] = kk; }
            }
        }
    }

    // cross-lane min over the 16 center-groups via monotone u64 keys
    // (smaller d2 wins; equal d2 -> smaller k), lane bits 2..5
    #pragma unroll
    for (int i = 0; i < 4; ++i) {
        unsigned int b = __float_as_uint(bd[i]);
        b = (b & 0x80000000u) ? ~b : (b | 0x80000000u);
        unsigned long long key = ((unsigned long long)b << 32)
                               | (unsigned int)bki[i];
        #pragma unroll
        for (int st = 4; st <= 32; st <<= 1) {
            unsigned long long o = __shfl_xor(key, st, 64);
            if (o < key) key = o;
        }
        if (cg == 0) {
            int p = blockIdx.x * 64 + w * 16 + pg * 4 + i;
            int k = (int)(unsigned int)key;
            asn[p] = k;
            out_f[p] = (float)k;
        }
    }
}

// ---------------------------------------------------------------------------
// accumulate: 256 blocks = 64 chunks (2048 pts) x 4 dim-slices (16 dims).
// INT64 FIXED-POINT (scale 2^40) LDS + global atomics: integer addition is
// exactly order-independent -> bit-deterministic across graph replays.
// ---------------------------------------------------------------------------
__global__ __launch_bounds__(256) void accum_kernel(
        const float* __restrict__ X, const int* __restrict__ asn,
        unsigned long long* __restrict__ qsums, int* __restrict__ counts) {
    __shared__ unsigned long long lsum[KC * 16];   // 64 KB
    __shared__ int lcnt[KC];
    int slice = blockIdx.x & 3;
    int chunk = blockIdx.x >> 2;
    int p4 = threadIdx.x >> 2;   // 0..63: point lane
    int c4 = threadIdx.x & 3;    // float4 slot within the 16-dim slice

    for (int i = threadIdx.x; i < KC * 16; i += 256) lsum[i] = 0ull;
    for (int i = threadIdx.x; i < KC; i += 256) lcnt[i] = 0;
    __syncthreads();

    int base = chunk * CHUNK_PTS;
    #pragma unroll 2
    for (int it = 0; it < CHUNK_PTS / 64; ++it) {
        int n = base + it * 64 + p4;
        int a = asn[n];
        float4 xv = *(const float4*)(X + (size_t)n * DIM + slice * 16 + c4 * 4);
        long long q0 = (long long)llrint((double)xv.x * FIXSCALE);
        long long q1 = (long long)llrint((double)xv.y * FIXSCALE);
        long long q2 = (long long)llrint((double)xv.z * FIXSCALE);
        long long q3 = (long long)llrint((double)xv.w * FIXSCALE);
        atomicAdd(&lsum[a * 16 + c4 * 4 + 0], (unsigned long long)q0);
        atomicAdd(&lsum[a * 16 + c4 * 4 + 1], (unsigned long long)q1);
        atomicAdd(&lsum[a * 16 + c4 * 4 + 2], (unsigned long long)q2);
        atomicAdd(&lsum[a * 16 + c4 * 4 + 3], (unsigned long long)q3);
        if (slice == 0 && c4 == 0) atomicAdd(&lcnt[a], 1);
    }
    __syncthreads();

    for (int i = threadIdx.x; i < KC * 16; i += 256) {
        unsigned long long v = lsum[i];
        if (v != 0ull) {
            int k  = i >> 4;
            int dd = i & 15;
            atomicAdd(&qsums[k * DIM + slice * 16 + dd], v);
        }
    }
    if (slice == 0)
        for (int i = threadIdx.x; i < KC; i += 256) {
            int v = lcnt[i];
            if (v != 0) atomicAdd(&counts[i], v);
        }
}

// ---------------------------------------------------------------------------
// update: new_centers = sums / max(counts,1); element-wise ==0 entries
// re-seeded from X[repl_idx[i]]. Fuses next iteration's c2 via butterfly
// shuffle (identical summation tree to c2_kernel). One wave per cluster.
// ---------------------------------------------------------------------------
__global__ __launch_bounds__(256) void update_kernel(
        const unsigned long long* __restrict__ qsums,
        const int* __restrict__ counts,
        const int* __restrict__ repl, const float* __restrict__ X,
        float* __restrict__ Cws, float* __restrict__ outC,
        float* __restrict__ c2v) {
    int k = blockIdx.x * 4 + (threadIdx.x >> 6);
    int d = threadIdx.x & 63;

    long long q = (long long)qsums[k * DIM + d];
    float s = (float)((double)q * (1.0 / FIXSCALE));
    float cnt = (float)counts[k];
    float v = s / fmaxf(cnt, 1.0f);
    if (v == 0.0f) v = X[(size_t)repl[k] * DIM + d];
    Cws[k * DIM + d]  = v;
    outC[k * DIM + d] = v;

    float sq = v * v;
    #pragma unroll
    for (int st = 1; st < 64; st <<= 1)
        sq += __shfl_xor(sq, st, 64);
    if (d == 0) c2v[k] = sq;
}

// ---------------------------------------------------------------------------
extern "C" void kernel_launch(void* const* d_in, const int* in_sizes, int n_in,
                              void* d_out, int out_size, void* d_ws, size_t ws_size,
                              hipStream_t stream) {
    const float* X    = (const float*)d_in[0];   // [N, D]
    const float* C0   = (const float*)d_in[1];   // [K, D]
    const int*   repl = (const int*)d_in[2];     // [MAXIT, K]
    float* out = (float*)d_out;                  // [N] assignments + [K*D] centers

    // Total ws footprint: 900 KB (round 2's 920 KB proved safe; round 3's
    // 12.8 MB failed with poison-pattern errors -> keep it small).
    char* ws = (char*)d_ws;
    int*   asn    = (int*)  (ws + 0);                        // 512 KB
    float* Cws    = (float*)(ws + (512 << 10));              // 128 KB
    unsigned long long* qsums = (unsigned long long*)(ws + (640 << 10)); // 256 KB
    int*   counts = (int*)  (ws + (896 << 10));              // 2 KB (contiguous w/ qsums)
    float* c2v    = (float*)(ws + (898 << 10));              // 2 KB

    c2_kernel<<<2, 256, 0, stream>>>(C0, c2v);

    for (int i = 0; i < MAXIT; ++i) {
        const float* C = (i == 0) ? C0 : Cws;

        assign_kernel<<<N_PTS / 64, 256, 0, stream>>>(X, C, c2v, asn, out);

        // zero qsums (256 KB) + counts (2 KB), contiguous
        hipMemsetAsync(qsums, 0, KC * DIM * sizeof(unsigned long long)
                                 + KC * sizeof(int), stream);

        accum_kernel<<<NCHUNK * 4, 256, 0, stream>>>(X, asn, qsums, counts);

        update_kernel<<<KC / 4, 256, 0, stream>>>(
            qsums, counts, repl + i * KC, X, Cws, out + N_PTS, c2v);
    }
}

// Round 10
// 713.107 us; speedup vs baseline: 1.2057x; 1.2057x over previous
//
#include <hip/hip_runtime.h>

#define N_PTS 131072
#define KC    512
#define DIM   64
#define MAXIT 5
#define NCHUNK 64
#define CHUNK_PTS (N_PTS / NCHUNK)    // 2048
#define FIXSCALE 1099511627776.0      // 2^40

typedef short v8s __attribute__((ext_vector_type(8)));
typedef float v4f __attribute__((ext_vector_type(4)));

// f32 -> bf16 bits, RTNE (normals; inputs are O(1) gaussians + residuals)
__device__ __forceinline__ unsigned short bf16_rtne(float x) {
    unsigned int u = __float_as_uint(x);
    return (unsigned short)((u + 0x7FFFu + ((u >> 16) & 1u)) >> 16);
}
__device__ __forceinline__ float bf16_f32(unsigned short b) {
    return __uint_as_float(((unsigned int)b) << 16);
}
// 3-way split: x == h + m + l exactly (24 mantissa bits captured; the two
// subtractions are exact residuals)
__device__ __forceinline__ void split3(float x, short& h, short& m, short& l) {
    unsigned short hb = bf16_rtne(x);
    float r1 = x - bf16_f32(hb);
    unsigned short mb = bf16_rtne(r1);
    float r2 = r1 - bf16_f32(mb);
    h = (short)hb; m = (short)mb; l = (short)bf16_rtne(r2);
}

// ---------------------------------------------------------------------------
// prep (iter 0): c2[k] = sum C[k][d]^2 (round-2 tree, bit-identical) + 3-way
// bf16 split of C0 into Ch/Cm/Cl [512][64] row-major.
// ---------------------------------------------------------------------------
__global__ __launch_bounds__(256) void prep_kernel(
        const float* __restrict__ C, float* __restrict__ c2out,
        unsigned short* __restrict__ Ch, unsigned short* __restrict__ Cm,
        unsigned short* __restrict__ Cl) {
    int k = blockIdx.x * 256 + threadIdx.x;
    if (k < KC) {
        float sq[DIM];
        #pragma unroll
        for (int j = 0; j < DIM; ++j) {
            float c = C[k * DIM + j];
            sq[j] = c * c;
            short h, m, l;
            split3(c, h, m, l);
            Ch[k * DIM + j] = (unsigned short)h;
            Cm[k * DIM + j] = (unsigned short)m;
            Cl[k * DIM + j] = (unsigned short)l;
        }
        #pragma unroll
        for (int st = 1; st < DIM; st <<= 1)
            #pragma unroll
            for (int j = 0; j < DIM; j += 2 * st)
                sq[j] = sq[j] + sq[j + st];
        c2out[k] = sq[0];
    }
}

// ---------------------------------------------------------------------------
// assign kernel, ROUND 10: bf16 split MFMA.
// Block = 256 thr = 4 waves; wave owns 32 points (2 MFMA row-tiles of 16).
// Loop 32 center-tiles of 16; per (ctr-tile, point-tile): 12
// mfma_f32_16x16x32_bf16 = {hh,mh,hm,mm,lh,hl} x 2 k-chunks, acc f32.
// Fragment layouts (learn_hip m89/m120, HW-verified):
//   A[m=lane&15][k=(lane>>4)*8+j]   (m = point)
//   B[n=lane&15][k=(lane>>4)*8+j]   (n = center)
//   D: col(n)=lane&15, row(m)=(lane>>4)*4+reg
// d2 = (x2 + c2) - 2*dot: x2 (round-2 pairwise tree, bit-identical) + c2
// unchanged; dot deviation ~1e-6 << ULP(d2>=64) = 3.8e-6, absorbed by the
// final rounding (same sub-ULP argument that held for rounds 2-9).
// Argmin: ascending-ct strict '<' per lane, u64 monotone-key butterfly over
// the 16 lanes of each point-group -> exact jnp.argmin tie semantics.
// ---------------------------------------------------------------------------
__global__ __launch_bounds__(256) void assign_kernel(
        const float* __restrict__ X,
        const unsigned short* __restrict__ Ch,
        const unsigned short* __restrict__ Cm,
        const unsigned short* __restrict__ Cl,
        const float* __restrict__ c2v, float* __restrict__ out_f) {
    __shared__ float x2p[4][2][16][8];
    __shared__ float x2f[4][2][16];

    const int wv  = threadIdx.x >> 6;
    const int l   = threadIdx.x & 63;
    const int row = l & 15;       // A: point-in-tile; B: center-in-tile (D col)
    const int q   = l >> 4;       // k-quad; D rows = q*4+r
    const int pbase = blockIdx.x * 128 + wv * 32;

    // ---- A fragments (3 splits x 2 k-chunks x 2 point-tiles) + x2 partials
    v8s ah[2][2], am[2][2], al[2][2];
    #pragma unroll
    for (int T = 0; T < 2; ++T) {
        const float* xr = X + (size_t)(pbase + T * 16 + row) * DIM + q * 8;
        #pragma unroll
        for (int kc = 0; kc < 2; ++kc) {
            float4 v0 = *(const float4*)(xr + kc * 32);
            float4 v1 = *(const float4*)(xr + kc * 32 + 4);
            float e[8] = { v0.x, v0.y, v0.z, v0.w, v1.x, v1.y, v1.z, v1.w };
            v8s H, M, L;
            #pragma unroll
            for (int j = 0; j < 8; ++j) {
                short hh, mm, ll;
                split3(e[j], hh, mm, ll);
                H[j] = hh; M[j] = mm; L[j] = ll;
            }
            ah[T][kc] = H; am[T][kc] = M; al[T][kc] = L;
            // aligned 8-leaf subtree of the round-2 x2 tree (exact order)
            float s0 = e[0]*e[0], s1 = e[1]*e[1], s2 = e[2]*e[2], s3 = e[3]*e[3];
            float s4 = e[4]*e[4], s5 = e[5]*e[5], s6 = e[6]*e[6], s7 = e[7]*e[7];
            x2p[wv][T][row][kc * 4 + q] =
                ((s0 + s1) + (s2 + s3)) + ((s4 + s5) + (s6 + s7));
        }
    }
    __syncthreads();
    if (threadIdx.x < 128) {
        int w2 = threadIdx.x >> 5, T2 = (threadIdx.x >> 4) & 1, pt = threadIdx.x & 15;
        const float* P = x2p[w2][T2][pt];
        x2f[w2][T2][pt] = ((P[0] + P[1]) + (P[2] + P[3]))
                        + ((P[4] + P[5]) + (P[6] + P[7]));
    }
    __syncthreads();
    float x2x[2][4];
    #pragma unroll
    for (int T = 0; T < 2; ++T)
        #pragma unroll
        for (int r = 0; r < 4; ++r)
            x2x[T][r] = x2f[wv][T][q * 4 + r];

    float bd[2][4] = { {3.4e38f,3.4e38f,3.4e38f,3.4e38f},
                       {3.4e38f,3.4e38f,3.4e38f,3.4e38f} };
    int   bk[2][4] = { {0,0,0,0}, {0,0,0,0} };

    // ---- main loop over 32 center-tiles
    for (int ct = 0; ct < 32; ++ct) {
        const size_t cb = (size_t)(ct * 16 + row) * DIM + q * 8;
        v8s bh0 = *(const v8s*)(Ch + cb);
        v8s bh1 = *(const v8s*)(Ch + cb + 32);
        v8s bm0 = *(const v8s*)(Cm + cb);
        v8s bm1 = *(const v8s*)(Cm + cb + 32);
        v8s bl0 = *(const v8s*)(Cl + cb);
        v8s bl1 = *(const v8s*)(Cl + cb + 32);
        float c2k = c2v[ct * 16 + row];

        #pragma unroll
        for (int T = 0; T < 2; ++T) {
            v4f acc = {0.f, 0.f, 0.f, 0.f};
            acc = __builtin_amdgcn_mfma_f32_16x16x32_bf16(ah[T][0], bh0, acc, 0, 0, 0);
            acc = __builtin_amdgcn_mfma_f32_16x16x32_bf16(ah[T][1], bh1, acc, 0, 0, 0);
            acc = __builtin_amdgcn_mfma_f32_16x16x32_bf16(am[T][0], bh0, acc, 0, 0, 0);
            acc = __builtin_amdgcn_mfma_f32_16x16x32_bf16(am[T][1], bh1, acc, 0, 0, 0);
            acc = __builtin_amdgcn_mfma_f32_16x16x32_bf16(ah[T][0], bm0, acc, 0, 0, 0);
            acc = __builtin_amdgcn_mfma_f32_16x16x32_bf16(ah[T][1], bm1, acc, 0, 0, 0);
            acc = __builtin_amdgcn_mfma_f32_16x16x32_bf16(am[T][0], bm0, acc, 0, 0, 0);
            acc = __builtin_amdgcn_mfma_f32_16x16x32_bf16(am[T][1], bm1, acc, 0, 0, 0);
            acc = __builtin_amdgcn_mfma_f32_16x16x32_bf16(al[T][0], bh0, acc, 0, 0, 0);
            acc = __builtin_amdgcn_mfma_f32_16x16x32_bf16(al[T][1], bh1, acc, 0, 0, 0);
            acc = __builtin_amdgcn_mfma_f32_16x16x32_bf16(ah[T][0], bl0, acc, 0, 0, 0);
            acc = __builtin_amdgcn_mfma_f32_16x16x32_bf16(ah[T][1], bl1, acc, 0, 0, 0);
            #pragma unroll
            for (int r = 0; r < 4; ++r) {
                float tt = x2x[T][r] + c2k;
                float d2 = fmaf(-2.0f, acc[r], tt);
                if (d2 < bd[T][r]) { bd[T][r] = d2; bk[T][r] = ct * 16 + row; }
            }
        }
    }

    // ---- cross-lane argmin over the 16 center residues (lane bits 0..3)
    #pragma unroll
    for (int T = 0; T < 2; ++T)
        #pragma unroll
        for (int r = 0; r < 4; ++r) {
            unsigned int b = __float_as_uint(bd[T][r]);
            b = (b & 0x80000000u) ? ~b : (b | 0x80000000u);
            unsigned long long key = ((unsigned long long)b << 32)
                                   | (unsigned int)bk[T][r];
            #pragma unroll
            for (int st = 1; st <= 8; st <<= 1) {
                unsigned long long o = __shfl_xor(key, st, 64);
                if (o < key) key = o;
            }
            if (row == 0) {
                int p = pbase + T * 16 + q * 4 + r;
                out_f[p] = (float)((int)(unsigned int)key);
            }
        }
}

// ---------------------------------------------------------------------------
// accumulate: 256 blocks = 64 chunks x 4 dim-slices. INT64 fixed-point LDS +
// global atomics (order-independent -> bit-deterministic, round-5 proven).
// Assignments read from d_out as float (values 0..511, exact cast).
// ---------------------------------------------------------------------------
__global__ __launch_bounds__(256) void accum_kernel(
        const float* __restrict__ X, const float* __restrict__ af,
        unsigned long long* __restrict__ qsums, int* __restrict__ counts) {
    __shared__ unsigned long long lsum[KC * 16];   // 64 KB
    __shared__ int lcnt[KC];
    int slice = blockIdx.x & 3;
    int chunk = blockIdx.x >> 2;
    int p4 = threadIdx.x >> 2;
    int c4 = threadIdx.x & 3;

    for (int i = threadIdx.x; i < KC * 16; i += 256) lsum[i] = 0ull;
    for (int i = threadIdx.x; i < KC; i += 256) lcnt[i] = 0;
    __syncthreads();

    int base = chunk * CHUNK_PTS;
    #pragma unroll 2
    for (int it = 0; it < CHUNK_PTS / 64; ++it) {
        int n = base + it * 64 + p4;
        int a = (int)af[n];
        float4 xv = *(const float4*)(X + (size_t)n * DIM + slice * 16 + c4 * 4);
        long long q0 = (long long)llrint((double)xv.x * FIXSCALE);
        long long q1 = (long long)llrint((double)xv.y * FIXSCALE);
        long long q2 = (long long)llrint((double)xv.z * FIXSCALE);
        long long q3 = (long long)llrint((double)xv.w * FIXSCALE);
        atomicAdd(&lsum[a * 16 + c4 * 4 + 0], (unsigned long long)q0);
        atomicAdd(&lsum[a * 16 + c4 * 4 + 1], (unsigned long long)q1);
        atomicAdd(&lsum[a * 16 + c4 * 4 + 2], (unsigned long long)q2);
        atomicAdd(&lsum[a * 16 + c4 * 4 + 3], (unsigned long long)q3);
        if (slice == 0 && c4 == 0) atomicAdd(&lcnt[a], 1);
    }
    __syncthreads();

    for (int i = threadIdx.x; i < KC * 16; i += 256) {
        unsigned long long v = lsum[i];
        if (v != 0ull)
            atomicAdd(&qsums[(i >> 4) * DIM + slice * 16 + (i & 15)], v);
    }
    if (slice == 0)
        for (int i = threadIdx.x; i < KC; i += 256) {
            int v = lcnt[i];
            if (v != 0) atomicAdd(&counts[i], v);
        }
}

// ---------------------------------------------------------------------------
// update: centers = sums/max(cnt,1), ==0 -> re-seed; writes f32 centers to
// d_out, next iter's c2 (butterfly, same tree) AND the 3-way bf16 splits.
// ---------------------------------------------------------------------------
__global__ __launch_bounds__(256) void update_kernel(
        const unsigned long long* __restrict__ qsums,
        const int* __restrict__ counts,
        const int* __restrict__ repl, const float* __restrict__ X,
        float* __restrict__ outC, float* __restrict__ c2v,
        unsigned short* __restrict__ Ch, unsigned short* __restrict__ Cm,
        unsigned short* __restrict__ Cl) {
    int k = blockIdx.x * 4 + (threadIdx.x >> 6);
    int d = threadIdx.x & 63;

    long long qq = (long long)qsums[k * DIM + d];
    float s = (float)((double)qq * (1.0 / FIXSCALE));
    float cnt = (float)counts[k];
    float v = s / fmaxf(cnt, 1.0f);
    if (v == 0.0f) v = X[(size_t)repl[k] * DIM + d];
    outC[k * DIM + d] = v;

    short h, m, l;
    split3(v, h, m, l);
    Ch[k * DIM + d] = (unsigned short)h;
    Cm[k * DIM + d] = (unsigned short)m;
    Cl[k * DIM + d] = (unsigned short)l;

    float sq = v * v;
    #pragma unroll
    for (int st = 1; st < 64; st <<= 1)
        sq += __shfl_xor(sq, st, 64);
    if (d == 0) c2v[k] = sq;
}

// ---------------------------------------------------------------------------
extern "C" void kernel_launch(void* const* d_in, const int* in_sizes, int n_in,
                              void* d_out, int out_size, void* d_ws, size_t ws_size,
                              hipStream_t stream) {
    const float* X    = (const float*)d_in[0];   // [N, D]
    const float* C0   = (const float*)d_in[1];   // [K, D]
    const int*   repl = (const int*)d_in[2];     // [MAXIT, K]
    float* out = (float*)d_out;                  // [N] assignments + [K*D] centers

    // ws: 452 KB total (round-2's 920 KB proved safe; round-3's 12.8 MB did
    // not). Assignments live in d_out; f32 centers live in d_out's tail.
    char* ws = (char*)d_ws;
    unsigned short* Ch = (unsigned short*)(ws + 0);            // 64 KB
    unsigned short* Cm = (unsigned short*)(ws + (64 << 10));   // 64 KB
    unsigned short* Cl = (unsigned short*)(ws + (128 << 10));  // 64 KB
    unsigned long long* qsums = (unsigned long long*)(ws + (192 << 10)); // 256 KB
    int*   counts = (int*)  (ws + (448 << 10));                // 2 KB
    float* c2v    = (float*)(ws + (450 << 10));                // 2 KB

    prep_kernel<<<2, 256, 0, stream>>>(C0, c2v, Ch, Cm, Cl);

    for (int i = 0; i < MAXIT; ++i) {
        assign_kernel<<<N_PTS / 128, 256, 0, stream>>>(
            X, Ch, Cm, Cl, c2v, out);

        hipMemsetAsync(qsums, 0, KC * DIM * sizeof(unsigned long long)
                                 + KC * sizeof(int), stream);

        accum_kernel<<<NCHUNK * 4, 256, 0, stream>>>(X, out, qsums, counts);

        update_kernel<<<KC / 4, 256, 0, stream>>>(
            qsums, counts, repl + i * KC, X, out + N_PTS, c2v, Ch, Cm, Cl);
    }
}

// Round 11
// 634.924 us; speedup vs baseline: 1.3541x; 1.1231x over previous
//
#include <hip/hip_runtime.h>

#define N_PTS 131072
#define KC    512
#define DIM   64
#define MAXIT 5
#define NCHUNK 64
#define CHUNK_PTS (N_PTS / NCHUNK)    // 2048
#define FIXSCALE 1099511627776.0      // 2^40

typedef short v8s __attribute__((ext_vector_type(8)));
typedef float v4f __attribute__((ext_vector_type(4)));

// f32 -> bf16 bits, RTNE (normals; inputs are O(1) gaussians + residuals)
__device__ __forceinline__ unsigned short bf16_rtne(float x) {
    unsigned int u = __float_as_uint(x);
    return (unsigned short)((u + 0x7FFFu + ((u >> 16) & 1u)) >> 16);
}
__device__ __forceinline__ float bf16_f32(unsigned short b) {
    return __uint_as_float(((unsigned int)b) << 16);
}
// 3-way split: x == h + m + l exactly (24 mantissa bits captured)
__device__ __forceinline__ void split3(float x, short& h, short& m, short& l) {
    unsigned short hb = bf16_rtne(x);
    float r1 = x - bf16_f32(hb);
    unsigned short mb = bf16_rtne(r1);
    float r2 = r1 - bf16_f32(mb);
    h = (short)hb; m = (short)mb; l = (short)bf16_rtne(r2);
}

// ---------------------------------------------------------------------------
// prep (iter 0): c2[k] (round-2 tree, bit-identical) + 3-way bf16 split of C0.
// ---------------------------------------------------------------------------
__global__ __launch_bounds__(256) void prep_kernel(
        const float* __restrict__ C, float* __restrict__ c2out,
        unsigned short* __restrict__ Ch, unsigned short* __restrict__ Cm,
        unsigned short* __restrict__ Cl) {
    int k = blockIdx.x * 256 + threadIdx.x;
    if (k < KC) {
        float sq[DIM];
        #pragma unroll
        for (int j = 0; j < DIM; ++j) {
            float c = C[k * DIM + j];
            sq[j] = c * c;
            short h, m, l;
            split3(c, h, m, l);
            Ch[k * DIM + j] = (unsigned short)h;
            Cm[k * DIM + j] = (unsigned short)m;
            Cl[k * DIM + j] = (unsigned short)l;
        }
        #pragma unroll
        for (int st = 1; st < DIM; st <<= 1)
            #pragma unroll
            for (int j = 0; j < DIM; j += 2 * st)
                sq[j] = sq[j] + sq[j + st];
        c2out[k] = sq[0];
    }
}

// ---------------------------------------------------------------------------
// assign kernel, ROUND 11: round-10 bf16-split MFMA (bit-identical numerics)
// with (a) 64 points/wave — 4 row-tiles per B-load batch (48 MFMA / 6 loads,
// 4x amortization vs round 10) and (b) register double-buffer prefetch of
// the next center-tile's B fragments + c2 (loads in flight across a full
// 48-MFMA batch; round 10 exposed ~300cyc L2 latency per tile at MfmaUtil
// 16%). Grid halves to 512 blocks; 2 waves/SIMD unchanged -> prefetch costs
// no occupancy this time (round-9 lesson).
// Fragment layouts (HW-verified, round-10 passing): A[m=lane&15][k=q*8+j],
// B[n=lane&15][k=q*8+j], D col=lane&15, row=q*4+reg.
// ---------------------------------------------------------------------------
__global__ __launch_bounds__(256) void assign_kernel(
        const float* __restrict__ X,
        const unsigned short* __restrict__ Ch,
        const unsigned short* __restrict__ Cm,
        const unsigned short* __restrict__ Cl,
        const float* __restrict__ c2v, float* __restrict__ out_f) {
    __shared__ float x2p[4][4][16][8];   // 8 KB
    __shared__ float x2f[4][4][16];      // 1 KB

    const int wv  = threadIdx.x >> 6;
    const int l   = threadIdx.x & 63;
    const int row = l & 15;       // A: point-in-tile; B: center-in-tile (D col)
    const int q   = l >> 4;       // k-quad; D rows = q*4+r
    const int pbase = blockIdx.x * 256 + wv * 64;

    // ---- A fragments (3 splits x 2 k-chunks x 4 point-tiles) + x2 partials
    v8s ah[4][2], am[4][2], al[4][2];
    #pragma unroll
    for (int T = 0; T < 4; ++T) {
        const float* xr = X + (size_t)(pbase + T * 16 + row) * DIM + q * 8;
        #pragma unroll
        for (int kc = 0; kc < 2; ++kc) {
            float4 v0 = *(const float4*)(xr + kc * 32);
            float4 v1 = *(const float4*)(xr + kc * 32 + 4);
            float e[8] = { v0.x, v0.y, v0.z, v0.w, v1.x, v1.y, v1.z, v1.w };
            v8s H, M, L;
            #pragma unroll
            for (int j = 0; j < 8; ++j) {
                short hh, mm, ll;
                split3(e[j], hh, mm, ll);
                H[j] = hh; M[j] = mm; L[j] = ll;
            }
            ah[T][kc] = H; am[T][kc] = M; al[T][kc] = L;
            // aligned 8-leaf subtree of the round-2 x2 tree (exact order)
            float s0 = e[0]*e[0], s1 = e[1]*e[1], s2 = e[2]*e[2], s3 = e[3]*e[3];
            float s4 = e[4]*e[4], s5 = e[5]*e[5], s6 = e[6]*e[6], s7 = e[7]*e[7];
            x2p[wv][T][row][kc * 4 + q] =
                ((s0 + s1) + (s2 + s3)) + ((s4 + s5) + (s6 + s7));
        }
    }
    __syncthreads();
    {   // 256 threads reduce all 4x4x16 rows (same tree as rounds 2-10)
        int w2 = threadIdx.x >> 6, T2 = (threadIdx.x >> 4) & 3, pt = threadIdx.x & 15;
        const float* P = x2p[w2][T2][pt];
        x2f[w2][T2][pt] = ((P[0] + P[1]) + (P[2] + P[3]))
                        + ((P[4] + P[5]) + (P[6] + P[7]));
    }
    __syncthreads();
    float x2x[4][4];
    #pragma unroll
    for (int T = 0; T < 4; ++T)
        #pragma unroll
        for (int r = 0; r < 4; ++r)
            x2x[T][r] = x2f[wv][T][q * 4 + r];

    float bd[4][4];
    int   bk[4][4];
    #pragma unroll
    for (int T = 0; T < 4; ++T)
        #pragma unroll
        for (int r = 0; r < 4; ++r) { bd[T][r] = 3.4e38f; bk[T][r] = 0; }

    // ---- prefetch center-tile 0 into registers
    v8s nbh0, nbh1, nbm0, nbm1, nbl0, nbl1;
    float nc2k;
    {
        const size_t cb = (size_t)row * DIM + q * 8;
        nbh0 = *(const v8s*)(Ch + cb);
        nbh1 = *(const v8s*)(Ch + cb + 32);
        nbm0 = *(const v8s*)(Cm + cb);
        nbm1 = *(const v8s*)(Cm + cb + 32);
        nbl0 = *(const v8s*)(Cl + cb);
        nbl1 = *(const v8s*)(Cl + cb + 32);
        nc2k = c2v[row];
    }

    // ---- main loop over 32 center-tiles, register double-buffered
    for (int ct = 0; ct < 32; ++ct) {
        v8s bh0 = nbh0, bh1 = nbh1, bm0 = nbm0, bm1 = nbm1,
            bl0 = nbl0, bl1 = nbl1;
        float c2k = nc2k;
        {   // prefetch ct+1 (wraps to 0 on last iter: in-bounds, unused)
            int ctn = (ct + 1) & 31;
            const size_t cb = (size_t)(ctn * 16 + row) * DIM + q * 8;
            nbh0 = *(const v8s*)(Ch + cb);
            nbh1 = *(const v8s*)(Ch + cb + 32);
            nbm0 = *(const v8s*)(Cm + cb);
            nbm1 = *(const v8s*)(Cm + cb + 32);
            nbl0 = *(const v8s*)(Cl + cb);
            nbl1 = *(const v8s*)(Cl + cb + 32);
            nc2k = c2v[ctn * 16 + row];
        }

        #pragma unroll
        for (int T = 0; T < 4; ++T) {
            v4f acc = {0.f, 0.f, 0.f, 0.f};
            acc = __builtin_amdgcn_mfma_f32_16x16x32_bf16(ah[T][0], bh0, acc, 0, 0, 0);
            acc = __builtin_amdgcn_mfma_f32_16x16x32_bf16(ah[T][1], bh1, acc, 0, 0, 0);
            acc = __builtin_amdgcn_mfma_f32_16x16x32_bf16(am[T][0], bh0, acc, 0, 0, 0);
            acc = __builtin_amdgcn_mfma_f32_16x16x32_bf16(am[T][1], bh1, acc, 0, 0, 0);
            acc = __builtin_amdgcn_mfma_f32_16x16x32_bf16(ah[T][0], bm0, acc, 0, 0, 0);
            acc = __builtin_amdgcn_mfma_f32_16x16x32_bf16(ah[T][1], bm1, acc, 0, 0, 0);
            acc = __builtin_amdgcn_mfma_f32_16x16x32_bf16(am[T][0], bm0, acc, 0, 0, 0);
            acc = __builtin_amdgcn_mfma_f32_16x16x32_bf16(am[T][1], bm1, acc, 0, 0, 0);
            acc = __builtin_amdgcn_mfma_f32_16x16x32_bf16(al[T][0], bh0, acc, 0, 0, 0);
            acc = __builtin_amdgcn_mfma_f32_16x16x32_bf16(al[T][1], bh1, acc, 0, 0, 0);
            acc = __builtin_amdgcn_mfma_f32_16x16x32_bf16(ah[T][0], bl0, acc, 0, 0, 0);
            acc = __builtin_amdgcn_mfma_f32_16x16x32_bf16(ah[T][1], bl1, acc, 0, 0, 0);
            #pragma unroll
            for (int r = 0; r < 4; ++r) {
                float tt = x2x[T][r] + c2k;
                float d2 = fmaf(-2.0f, acc[r], tt);
                if (d2 < bd[T][r]) { bd[T][r] = d2; bk[T][r] = ct * 16 + row; }
            }
        }
    }

    // ---- cross-lane argmin over the 16 center residues (lane bits 0..3)
    #pragma unroll
    for (int T = 0; T < 4; ++T)
        #pragma unroll
        for (int r = 0; r < 4; ++r) {
            unsigned int b = __float_as_uint(bd[T][r]);
            b = (b & 0x80000000u) ? ~b : (b | 0x80000000u);
            unsigned long long key = ((unsigned long long)b << 32)
                                   | (unsigned int)bk[T][r];
            #pragma unroll
            for (int st = 1; st <= 8; st <<= 1) {
                unsigned long long o = __shfl_xor(key, st, 64);
                if (o < key) key = o;
            }
            if (row == 0) {
                int p = pbase + T * 16 + q * 4 + r;
                out_f[p] = (float)((int)(unsigned int)key);
            }
        }
}

// ---------------------------------------------------------------------------
// accumulate: 256 blocks = 64 chunks x 4 dim-slices. INT64 fixed-point LDS +
// global atomics (order-independent -> bit-deterministic, round-5 proven).
// ---------------------------------------------------------------------------
__global__ __launch_bounds__(256) void accum_kernel(
        const float* __restrict__ X, const float* __restrict__ af,
        unsigned long long* __restrict__ qsums, int* __restrict__ counts) {
    __shared__ unsigned long long lsum[KC * 16];   // 64 KB
    __shared__ int lcnt[KC];
    int slice = blockIdx.x & 3;
    int chunk = blockIdx.x >> 2;
    int p4 = threadIdx.x >> 2;
    int c4 = threadIdx.x & 3;

    for (int i = threadIdx.x; i < KC * 16; i += 256) lsum[i] = 0ull;
    for (int i = threadIdx.x; i < KC; i += 256) lcnt[i] = 0;
    __syncthreads();

    int base = chunk * CHUNK_PTS;
    #pragma unroll 2
    for (int it = 0; it < CHUNK_PTS / 64; ++it) {
        int n = base + it * 64 + p4;
        int a = (int)af[n];
        float4 xv = *(const float4*)(X + (size_t)n * DIM + slice * 16 + c4 * 4);
        long long q0 = (long long)llrint((double)xv.x * FIXSCALE);
        long long q1 = (long long)llrint((double)xv.y * FIXSCALE);
        long long q2 = (long long)llrint((double)xv.z * FIXSCALE);
        long long q3 = (long long)llrint((double)xv.w * FIXSCALE);
        atomicAdd(&lsum[a * 16 + c4 * 4 + 0], (unsigned long long)q0);
        atomicAdd(&lsum[a * 16 + c4 * 4 + 1], (unsigned long long)q1);
        atomicAdd(&lsum[a * 16 + c4 * 4 + 2], (unsigned long long)q2);
        atomicAdd(&lsum[a * 16 + c4 * 4 + 3], (unsigned long long)q3);
        if (slice == 0 && c4 == 0) atomicAdd(&lcnt[a], 1);
    }
    __syncthreads();

    for (int i = threadIdx.x; i < KC * 16; i += 256) {
        unsigned long long v = lsum[i];
        if (v != 0ull)
            atomicAdd(&qsums[(i >> 4) * DIM + slice * 16 + (i & 15)], v);
    }
    if (slice == 0)
        for (int i = threadIdx.x; i < KC; i += 256) {
            int v = lcnt[i];
            if (v != 0) atomicAdd(&counts[i], v);
        }
}

// ---------------------------------------------------------------------------
// update: centers = sums/max(cnt,1), ==0 -> re-seed; writes f32 centers to
// d_out tail, next iter's c2 (same butterfly tree) + 3-way bf16 splits.
// ---------------------------------------------------------------------------
__global__ __launch_bounds__(256) void update_kernel(
        const unsigned long long* __restrict__ qsums,
        const int* __restrict__ counts,
        const int* __restrict__ repl, const float* __restrict__ X,
        float* __restrict__ outC, float* __restrict__ c2v,
        unsigned short* __restrict__ Ch, unsigned short* __restrict__ Cm,
        unsigned short* __restrict__ Cl) {
    int k = blockIdx.x * 4 + (threadIdx.x >> 6);
    int d = threadIdx.x & 63;

    long long qq = (long long)qsums[k * DIM + d];
    float s = (float)((double)qq * (1.0 / FIXSCALE));
    float cnt = (float)counts[k];
    float v = s / fmaxf(cnt, 1.0f);
    if (v == 0.0f) v = X[(size_t)repl[k] * DIM + d];
    outC[k * DIM + d] = v;

    short h, m, l;
    split3(v, h, m, l);
    Ch[k * DIM + d] = (unsigned short)h;
    Cm[k * DIM + d] = (unsigned short)m;
    Cl[k * DIM + d] = (unsigned short)l;

    float sq = v * v;
    #pragma unroll
    for (int st = 1; st < 64; st <<= 1)
        sq += __shfl_xor(sq, st, 64);
    if (d == 0) c2v[k] = sq;
}

// ---------------------------------------------------------------------------
extern "C" void kernel_launch(void* const* d_in, const int* in_sizes, int n_in,
                              void* d_out, int out_size, void* d_ws, size_t ws_size,
                              hipStream_t stream) {
    const float* X    = (const float*)d_in[0];   // [N, D]
    const float* C0   = (const float*)d_in[1];   // [K, D]
    const int*   repl = (const int*)d_in[2];     // [MAXIT, K]
    float* out = (float*)d_out;                  // [N] assignments + [K*D] centers

    // ws: 452 KB total (round-2's 920 KB proved safe; round-3's 12.8 MB not).
    char* ws = (char*)d_ws;
    unsigned short* Ch = (unsigned short*)(ws + 0);            // 64 KB
    unsigned short* Cm = (unsigned short*)(ws + (64 << 10));   // 64 KB
    unsigned short* Cl = (unsigned short*)(ws + (128 << 10));  // 64 KB
    unsigned long long* qsums = (unsigned long long*)(ws + (192 << 10)); // 256 KB
    int*   counts = (int*)  (ws + (448 << 10));                // 2 KB
    float* c2v    = (float*)(ws + (450 << 10));                // 2 KB

    prep_kernel<<<2, 256, 0, stream>>>(C0, c2v, Ch, Cm, Cl);

    for (int i = 0; i < MAXIT; ++i) {
        assign_kernel<<<N_PTS / 256, 256, 0, stream>>>(
            X, Ch, Cm, Cl, c2v, out);

        hipMemsetAsync(qsums, 0, KC * DIM * sizeof(unsigned long long)
                                 + KC * sizeof(int), stream);

        accum_kernel<<<NCHUNK * 4, 256, 0, stream>>>(X, out, qsums, counts);

        update_kernel<<<KC / 4, 256, 0, stream>>>(
            qsums, counts, repl + i * KC, X, out + N_PTS, c2v, Ch, Cm, Cl);
    }
}